// Round 7
// baseline (14.173 us; speedup 1.0000x reference)
//
#include <hip/hip_runtime.h>
#include <float.h>

// Problem constants (from reference)
#define NB 5                    // N_BANDS
#define BB 256                  // B
#define LL 800                  // L
#define TT (NB * LL)            // 4000 values per batch row
#define NN (TT - NB)            // 3995 output diffs per row

constexpr int THR   = 1024;         // 16 waves per block
constexpr int BPR   = 2;            // blocks per row (value-range halves)
constexpr int GBUK  = 4096;         // global buckets (monotone map of [0,1000))
constexpr int NBUK  = GBUK / BPR;   // 2048 local buckets per block
constexpr int CAP   = 2560;         // per-block element capacity (mean 2000, std ~32)
constexpr int NV4   = TT / 4;       // 1000 float4 loads cover the row

__global__ __launch_bounds__(THR, 8)   // force VGPR<=64 -> 2 blocks/CU
void half_split_sort_diff(const float* __restrict__ in,
                          const int* __restrict__ ntotal,
                          float* __restrict__ out)
{
    __shared__ float scat[CAP];         // bucket-grouped own-half values
    __shared__ float srt[CAP];          // sorted own-half
    __shared__ int   cnt[NBUK];         // histogram (atomic returns in-bucket offset)
    __shared__ int   bstart[NBUK + 1];  // bucket begin; [NBUK] = m
    __shared__ int   wsum[16];          // per-wave scan totals
    __shared__ int   wcb[16];           // per-wave below-counts
    __shared__ float wpm[16];           // per-wave below-max

    const int blk   = blockIdx.x;
    const int b     = blk >> 1;         // row
    const int h     = blk & 1;          // value-range half
    const int tid   = threadIdx.x;
    const int lane  = tid & 63;
    const int wid   = tid >> 6;
    const int gbase = h * NBUK;
    const float scale = (float)GBUK / 1000.0f;   // monotone, vals in [0,1000)

    #pragma unroll
    for (int k = 0; k < NBUK / THR; ++k) cnt[tid + k * THR] = 0;
    __syncthreads();

    // ---- Phase 1: one float4 per thread (full row); keep own-half values,
    //      histogram atomic returns in-bucket arrival offset; count/max below.
    float v[4];
    int   lb[4];
    int   off[4];
    int   cb = 0;
    float pm = -FLT_MAX;
    if (tid < NV4) {
        int band = tid / 200;            // 200 float4 per (band,row) chunk of 800
        int l4   = tid - band * 200;
        float4 x4 = *(reinterpret_cast<const float4*>(in + (band * BB + b) * LL) + l4);
        float xs[4] = {x4.x, x4.y, x4.z, x4.w};
        #pragma unroll
        for (int k = 0; k < 4; ++k) {
            float x = xs[k];
            int g   = (int)(x * scale);
            g = g < 0 ? 0 : (g > GBUK - 1 ? GBUK - 1 : g);
            int l   = g - gbase;
            if (l < 0) {                 // strictly below my range
                ++cb; pm = fmaxf(pm, x);
                lb[k] = -1;
            } else if (l < NBUK) {       // mine
                v[k]  = x;
                lb[k] = l;
                off[k] = atomicAdd(&cnt[l], 1);
            } else {
                lb[k] = -1;
            }
        }
    } else {
        lb[0] = lb[1] = lb[2] = lb[3] = -1;
    }
    // wave-reduce below-count / below-max
    #pragma unroll
    for (int d = 1; d < 64; d <<= 1) {
        cb += __shfl_xor(cb, d);
        pm  = fmaxf(pm, __shfl_xor(pm, d));
    }
    if (lane == 0) { wcb[wid] = cb; wpm[wid] = pm; }
    __syncthreads();                    // also orders histogram atomics
    int   below = 0;
    float pred  = -FLT_MAX;
    #pragma unroll
    for (int w = 0; w < 16; ++w) { below += wcb[w]; pred = fmaxf(pred, wpm[w]); }

    // ---- Phase 2: exclusive prefix sum over 2048 local buckets (2/thread).
    int c0 = cnt[2 * tid];
    int c1 = cnt[2 * tid + 1];
    int s  = c0 + c1;
    int inc = s;
    #pragma unroll
    for (int d = 1; d < 64; d <<= 1) {
        int t = __shfl_up(inc, d);
        if (lane >= d) inc += t;
    }
    if (lane == 63) wsum[wid] = inc;
    __syncthreads();
    int wo = 0;
    #pragma unroll
    for (int w = 0; w < 16; ++w) wo += (w < wid) ? wsum[w] : 0;
    int run = (inc - s) + wo;
    bstart[2 * tid]     = run;
    bstart[2 * tid + 1] = run + c0;
    if (tid == THR - 1) bstart[NBUK] = run + s;   // m = own-half element count
    __syncthreads();
    const int m = bstart[NBUK];

    // ---- Phase 3: deterministic scatter — position = bstart[lb] + off.
    #pragma unroll
    for (int k = 0; k < 4; ++k) {
        if (lb[k] >= 0) {
            int p = bstart[lb[k]] + off[k];
            if (p < CAP) scat[p] = v[k];
        }
    }
    __syncthreads();

    // ---- Phase 4: rank-count by position over scat (equal work, ~2/thread).
    for (int i = tid; i < m; i += THR) {
        float x = scat[i];
        int g   = (int)(x * scale);
        g = g < 0 ? 0 : (g > GBUK - 1 ? GBUK - 1 : g);
        int l   = g - gbase;
        int lo  = bstart[l];
        int hi  = bstart[l + 1];
        int r   = lo;
        for (int j = lo; j < hi; ++j) {
            float w = scat[j];
            if (w < x || (w == x && j < i)) ++r;   // scat index = unique tie-break
        }
        srt[r] = x;
    }
    __syncthreads();

    // ---- Phase 5: diffs for this contiguous slice of the global sort.
    // Local r has global index below + r; out[i] = S[i+5] - S[i+4] -> i = below+r-5.
    const int nt = ntotal[b];
    for (int r = tid; r < m; r += THR) {
        int i = below + r - NB;
        if (i >= 0 && i < NN) {
            float left = (r > 0) ? srt[r - 1] : pred;   // pred = S[below-1] exactly
            float d    = srt[r] - left;
            out[b * NN + i] = (i < nt) ? d : 0.0f;
        }
    }
}

extern "C" void kernel_launch(void* const* d_in, const int* in_sizes, int n_in,
                              void* d_out, int out_size, void* d_ws, size_t ws_size,
                              hipStream_t stream) {
    const float* in  = (const float*)d_in[0];   // (5, 256, 800) fp32
    const int*   nt  = (const int*)d_in[1];     // (256,) int32
    float*       out = (float*)d_out;           // (256, 3995) fp32
    (void)in_sizes; (void)n_in; (void)out_size; (void)d_ws; (void)ws_size;
    half_split_sort_diff<<<BB * BPR, THR, 0, stream>>>(in, nt, out);
}

// Round 8
// 11.753 us; speedup vs baseline: 1.2060x; 1.2060x over previous
//
#include <hip/hip_runtime.h>
#include <float.h>

// Problem constants (from reference)
#define NB 5                    // N_BANDS
#define BB 256                  // B
#define LL 800                  // L
#define TT (NB * LL)            // 4000 values per batch row
#define NN (TT - NB)            // 3995 output diffs per row

constexpr int BLOCK = 1024;     // 16 waves, one block per row
constexpr int NBUK  = 4096;     // lambda ~= 0.98
constexpr int NV4   = TT / 4;   // 1000 float4 loads cover the row exactly

__global__ __launch_bounds__(BLOCK)
void bucket_rank_diff4(const float* __restrict__ in,
                       const int* __restrict__ ntotal,
                       float* __restrict__ out)
{
    __shared__ __align__(16) float scat[TT];        // bucket-grouped values
    __shared__ __align__(16) float srt[TT + 8];     // sorted; +8 pad for b128 tail
    __shared__ __align__(16) int   cnt[NBUK];       // histogram (atomic returns offset); never overwritten
    __shared__ __align__(16) int   bstart[NBUK];    // bucket begin
    __shared__ int wsum[16];                        // per-wave scan totals

    const int b    = blockIdx.x;
    const int tid  = threadIdx.x;
    const int lane = tid & 63;
    const int wid  = tid >> 6;
    const bool active = (tid < NV4);
    const float scale = (float)NBUK / 1000.0f;      // monotone map, vals in [0,1000)

    // ---- Prefetch: issue global loads BEFORE init+barrier (latency hides).
    float4 x4 = make_float4(0.f, 0.f, 0.f, 0.f);
    if (active) {
        int band = tid / 200;            // 200 float4 per (band,row) chunk of 800
        int l4   = tid - band * 200;
        x4 = *(reinterpret_cast<const float4*>(in + (band * BB + b) * LL) + l4);
    }
    const int nt = ntotal[b];

    // init histogram: 4096 ints / 1024 threads = one int4 each
    *reinterpret_cast<int4*>(&cnt[tid * 4]) = make_int4(0, 0, 0, 0);
    __syncthreads();                                            // (1)

    // ---- Phase 1: classify; histogram atomic returns in-bucket arrival offset.
    float v[4];
    int   g[4];
    int   off[4];
    if (active) {
        v[0] = x4.x; v[1] = x4.y; v[2] = x4.z; v[3] = x4.w;
        #pragma unroll
        for (int k = 0; k < 4; ++k) {
            int gg = (int)(v[k] * scale);
            gg = gg < 0 ? 0 : (gg > NBUK - 1 ? NBUK - 1 : gg);
            g[k]   = gg;
            off[k] = atomicAdd(&cnt[gg], 1);
        }
    } else {
        g[0] = g[1] = g[2] = g[3] = -1;
    }
    __syncthreads();                                            // (2)

    // ---- Phase 2a: per-element bucket counts (independent of the scan below;
    //      cnt[] is final and never overwritten).
    int bc[4];
    #pragma unroll
    for (int k = 0; k < 4; ++k) bc[k] = (g[k] >= 0) ? cnt[g[k]] : 0;

    // ---- Phase 2b: exclusive prefix sum over 4096 bucket counts.
    int4 cq = *reinterpret_cast<int4*>(&cnt[tid * 4]);
    int  c0 = cq.x, c1 = cq.y, c2 = cq.z, c3 = cq.w;
    int  s  = c0 + c1 + c2 + c3;
    int  inc = s;
    #pragma unroll
    for (int d = 1; d < 64; d <<= 1) {
        int t = __shfl_up(inc, d);
        if (lane >= d) inc += t;
    }
    if (lane == 63) wsum[wid] = inc;
    __syncthreads();                                            // (3)
    int wo = 0;
    #pragma unroll
    for (int w = 0; w < 16; ++w) wo += (w < wid) ? wsum[w] : 0;
    int run = (inc - s) + wo;
    *reinterpret_cast<int4*>(&bstart[tid * 4]) =
        make_int4(run, run + c0, run + c0 + c1, run + c0 + c1 + c2);
    __syncthreads();                                            // (4)

    // ---- Phase 3: deterministic scatter; keep bucket base in registers.
    int pbase[4];
    if (active) {
        #pragma unroll
        for (int k = 0; k < 4; ++k) {
            pbase[k] = bstart[g[k]];
            scat[pbase[k] + off[k]] = v[k];
        }
    }
    __syncthreads();                                            // (5)

    // ---- Phase 4: rank-count within bucket — no bstart reads, singleton skip.
    if (active) {
        #pragma unroll
        for (int k = 0; k < 4; ++k) {
            int lo = pbase[k];
            if (bc[k] == 1) {
                srt[lo] = v[k];                 // ~37% of elements: rank known
            } else {
                float x = v[k];
                int   p = lo + off[k];          // my scat index (unique tie-break)
                int   r = lo;
                int   hi = lo + bc[k];
                for (int j = lo; j < hi; ++j) {
                    float w = scat[j];
                    if (w < x || (w == x && j < p)) ++r;
                }
                srt[r] = x;
            }
        }
    }
    __syncthreads();                                            // (6)

    // ---- Phase 5: adjacent diffs via two aligned b128 LDS reads per thread.
    // out[i] = srt[i+5] - srt[i+4]; let j0 = 4 + 4*tid (16B-aligned).
    if (tid < 999) {
        int j0 = 4 + 4 * tid;
        float4 q0 = *reinterpret_cast<const float4*>(&srt[j0]);
        float4 q1 = *reinterpret_cast<const float4*>(&srt[j0 + 4]);  // tail pad ok
        float d0 = q0.y - q0.x;
        float d1 = q0.z - q0.y;
        float d2 = q0.w - q0.z;
        float d3 = q1.x - q0.w;
        int i0 = 4 * tid;
        float* o = out + b * NN + i0;
        // nt <= NN-?; indices i0..i0+2 <= 3994 always valid; i0+3 == 3995 only at
        // tid==998, and nt <= 3995 makes (i < nt) false there — but we must still
        // guard the WRITE for i==3995 (out of row).
        o[0] = (i0     < nt) ? d0 : 0.0f;
        o[1] = (i0 + 1 < nt) ? d1 : 0.0f;
        o[2] = (i0 + 2 < nt) ? d2 : 0.0f;
        if (i0 + 3 < NN) o[3] = (i0 + 3 < nt) ? d3 : 0.0f;
    }
}

extern "C" void kernel_launch(void* const* d_in, const int* in_sizes, int n_in,
                              void* d_out, int out_size, void* d_ws, size_t ws_size,
                              hipStream_t stream) {
    const float* in  = (const float*)d_in[0];   // (5, 256, 800) fp32
    const int*   nt  = (const int*)d_in[1];     // (256,) int32
    float*       out = (float*)d_out;           // (256, 3995) fp32
    (void)in_sizes; (void)n_in; (void)out_size; (void)d_ws; (void)ws_size;
    bucket_rank_diff4<<<BB, BLOCK, 0, stream>>>(in, nt, out);
}